// Round 4
// baseline (396.219 us; speedup 1.0000x reference)
//
#include <hip/hip_runtime.h>
#include <hip/hip_bf16.h>

// ModulatedConv2d: B=8, Cin=Cout=512, K=3, H=W=64, pad=1, groups=B.
// bf16 MFMA implicit GEMM per batch: C[512,4096] = Wmod[512,4608] x Im2col.
// k = tap*512 + cin; BK=64, 2-barrier K-loop (R2 structure — best measured).
// This round: 32x32x16 MFMA (higher ceiling, half the issue slots) and
// border-zeroing fused into xpose_k (memset dispatch removed).

#define CIN   512
#define COUT  512
#define KDIM  4608        // 9 * 512
#define HWPIX 4096

typedef __attribute__((ext_vector_type(8)))  __bf16 bf16x8;
typedef __attribute__((ext_vector_type(16))) float  f32x16;

__device__ __forceinline__ unsigned short f2bf(float f){
  union { float f; unsigned int u; } v; v.f = f;
  unsigned int u = v.u;
  u += 0x7fffu + ((u >> 16) & 1u);     // round-to-nearest-even
  return (unsigned short)(u >> 16);
}

#define GLDS16(g, l) __builtin_amdgcn_global_load_lds(                      \
    (const __attribute__((address_space(1))) unsigned int*)(g),             \
    (__attribute__((address_space(3))) unsigned int*)(l), 16, 0, 0)

// ---------------- styles: s[b][c] = dot(w[b], affine_w[c]) + ab[c] + 1 ----
__global__ void style_k(const float* __restrict__ w, const float* __restrict__ aw,
                        const float* __restrict__ ab, float* __restrict__ styles){
  int wid = threadIdx.x >> 6, lane = threadIdx.x & 63;
  int gid = blockIdx.x * 4 + wid;           // 0..4095 = b*512 + c
  int b = gid >> 9, c = gid & 511;
  const float* wb = w + b * 512;
  const float* ar = aw + c * 512;
  float sum = 0.f;
  for (int j = lane; j < 512; j += 64) sum += wb[j] * ar[j];
  for (int off = 32; off; off >>= 1) sum += __shfl_down(sum, off, 64);
  if (lane == 0) styles[gid] = sum + ab[c] + 1.0f;
}

// ------------- modulate + demodulate -> bf16 wmod[b][o][tap*512+cin] ------
__global__ void modw_k(const float* __restrict__ weight, const float* __restrict__ styles,
                       unsigned short* __restrict__ wmod){
  int o = blockIdx.x, b = blockIdx.y;
  int t = threadIdx.x;
  const float* wrow = weight + (size_t)o * KDIM;   // weight[0][o][i][ky][kx]
  const float* st   = styles + b * 512;
  __shared__ unsigned short sw[9 * 520];           // tap stride 520 (pad vs 512)
  __shared__ float red[4];
  float vals[18];
  float part = 0.f;
#pragma unroll
  for (int it = 0; it < 18; ++it){
    int idx = it * 256 + t;             // coalesced over threads
    int i = idx / 9;
    float v = wrow[idx] * st[i];
    vals[it] = v;
    part += v * v;
  }
  int wid = t >> 6, lane = t & 63;
  for (int off = 32; off; off >>= 1) part += __shfl_down(part, off, 64);
  if (lane == 0) red[wid] = part;
  __syncthreads();
  float d = rsqrtf(red[0] + red[1] + red[2] + red[3] + 1e-8f);
#pragma unroll
  for (int it = 0; it < 18; ++it){
    int idx = it * 256 + t;
    int i = idx / 9;
    int tap = idx - i * 9;
    sw[tap * 520 + i] = f2bf(vals[it] * d);
  }
  __syncthreads();
  unsigned int* orow32 = (unsigned int*)(wmod + ((size_t)(b * 512 + o)) * KDIM);
#pragma unroll
  for (int it = 0; it < 9; ++it){       // 2304 dwords, fully coalesced
    int u = it * 256 + t;
    int e = u * 2;
    int tap2 = e >> 9, i2 = e & 511;
    orow32[u] = *(const unsigned int*)&sw[tap2 * 520 + i2];
  }
}

// ----- transpose+pad: x[b][c][h][w] fp32 -> xpad[b][h+1][w+1][c] bf16 -----
// Also zeroes the pad border (w=0/65 for its row; rows 0/65 from h=0/63 blocks),
// replacing the separate 35.7 MB memset dispatch.
__global__ void xpose_k(const float* __restrict__ x, unsigned short* __restrict__ xpad){
  int h = blockIdx.x, cg = blockIdx.y, b = blockIdx.z;
  int c0 = cg * 64;
  __shared__ unsigned short lds[64][66];   // [w][c]: writes 2-way (free), reads clean
  int t = threadIdx.x;
  const float* xb = x + (((size_t)(b * 512 + c0)) * 64 + h) * 64;
#pragma unroll
  for (int it = 0; it < 16; ++it){
    int idx = it * 256 + t;
    int cl = idx >> 6, wl = idx & 63;     // cl wave-uniform, wl = lane
    lds[wl][cl] = f2bf(xb[(size_t)cl * 4096 + wl]);
  }
  // border zeroing (independent of LDS): w=0 and w=65 for row h+1
  if (t < 64){
    int which = t >> 5;                   // 0: w=0, 1: w=65
    int ch2 = (t & 31) * 2;
    int wl = which ? 65 : 0;
    *(unsigned int*)&xpad[(((size_t)b * 66 + h + 1) * 66 + wl) * 512 + c0 + ch2] = 0u;
  }
  if (h == 0 || h == 63){                 // rows 0 / 65, all 66 w
    int row = (h == 0) ? 0 : 65;
    for (int u = t; u < 66 * 32; u += 256){
      int wl = u >> 5, ch2 = (u & 31) * 2;
      *(unsigned int*)&xpad[(((size_t)b * 66 + row) * 66 + wl) * 512 + c0 + ch2] = 0u;
    }
  }
  __syncthreads();
#pragma unroll
  for (int it = 0; it < 2; ++it){
    int idx = it * 256 + t;
    int wl = idx >> 3, ch = idx & 7;
    unsigned int u0 = *(const unsigned int*)&lds[wl][ch * 8 + 0];
    unsigned int u1 = *(const unsigned int*)&lds[wl][ch * 8 + 2];
    unsigned int u2 = *(const unsigned int*)&lds[wl][ch * 8 + 4];
    unsigned int u3 = *(const unsigned int*)&lds[wl][ch * 8 + 6];
    int off = ((b * 66 + h + 1) * 66 + (wl + 1)) * 512 + c0 + ch * 8;
    *(uint4*)&xpad[off] = make_uint4(u0, u1, u2, u3);
  }
}

// --------------------------- main conv GEMM ------------------------------
// 1-D grid 1024, XCD-swizzled; 128x128 tile, BK=64, 2-barrier K-loop,
// 32x32x16 bf16 MFMA, 2x2 tiles of 32x32 per wave (64x64 footprint).
__global__ __launch_bounds__(256, 4) void conv_gemm(
    const unsigned short* __restrict__ wmod, const unsigned short* __restrict__ xpad,
    const float* __restrict__ noise, const float* __restrict__ bias,
    float* __restrict__ out){
  __shared__ unsigned short As[2][128 * 32];   // [slice][m][k32]
  __shared__ unsigned short Bs[2][128 * 32];   // [slice][n][k32]
  // XCD swizzle: all 32 n-tiles of one (b, mtile) share g % 8 -> one XCD.
  int g = blockIdx.x;
  int xcd = g & 7, sl = g >> 3;
  int grp = xcd * 4 + (sl >> 5);   // 0..31 = b*4 + mt
  int nt  = sl & 31;
  int b = grp >> 2, mt = grp & 3;
  int m0 = mt * 128, n0 = nt * 128;
  int h0 = n0 >> 6;                         // 2 image rows per n-tile
  int tid = threadIdx.x, wid = tid >> 6, lane = tid & 63;
  int wm = wid >> 1, wn = wid & 1;
  int lr = lane >> 2;                       // row within 16-row staging group
  int lc = lane & 3;                        // 16B chunk within 64B row

  const unsigned short* wbase = wmod + ((size_t)(b * 512 + m0)) * KDIM;
  int aoff0 = ((wid * 2 + 0) * 16 + lr) * KDIM + lc * 8;
  int aoff1 = ((wid * 2 + 1) * 16 + lr) * KDIM + lc * 8;

  const unsigned short* xb = xpad + (size_t)b * 66 * 66 * 512;
  int p0 = (wid * 2 + 0) * 16 + lr;
  int p1 = (wid * 2 + 1) * 16 + lr;
  int boff0 = ((h0 + (p0 >> 6) + 1) * 66 + ((p0 & 63) + 1)) * 512 + lc * 8;
  int boff1 = ((h0 + (p1 >> 6) + 1) * 66 + ((p1 & 63) + 1)) * 512 + lc * 8;

  int lbase0 = (wid * 2 + 0) * 512;         // wave-uniform LDS element offsets
  int lbase1 = (wid * 2 + 1) * 512;

  // 32x32x16 fragment addressing: A[m=lane&31][k=(lane>>5)*8+j]
  int ln31 = lane & 31;
  int hi8  = (lane >> 5) * 8;
  int apo[2], bpo[2];
#pragma unroll
  for (int i = 0; i < 2; ++i){
    apo[i] = (wm * 64 + i * 32 + ln31) * 32 + hi8;
    bpo[i] = (wn * 64 + i * 32 + ln31) * 32 + hi8;
  }

  f32x16 acc[2][2];
#pragma unroll
  for (int i = 0; i < 2; ++i)
#pragma unroll
    for (int j = 0; j < 2; ++j)
#pragma unroll
      for (int r = 0; r < 16; ++r) acc[i][j][r] = 0.f;

  for (int ks = 0; ks < 72; ++ks){
    int tap = ks >> 3;                      // 64 | 512: one tap per BK=64 step
    int c0  = (ks & 7) << 6;
    int k0  = (tap << 9) + c0;              // == ks*64
    int dy3 = tap / 3;
    int bshift = (((dy3 - 1) * 66 + (tap - dy3 * 3 - 1)) << 9) + c0;
    __syncthreads();                        // prior iter's ds_reads retired
    GLDS16(wbase + aoff0 + k0,      &As[0][lbase0]);
    GLDS16(wbase + aoff1 + k0,      &As[0][lbase1]);
    GLDS16(wbase + aoff0 + k0 + 32, &As[1][lbase0]);
    GLDS16(wbase + aoff1 + k0 + 32, &As[1][lbase1]);
    GLDS16(xb + boff0 + bshift,      &Bs[0][lbase0]);
    GLDS16(xb + boff1 + bshift,      &Bs[0][lbase1]);
    GLDS16(xb + boff0 + bshift + 32, &Bs[1][lbase0]);
    GLDS16(xb + boff1 + bshift + 32, &Bs[1][lbase1]);
    __syncthreads();                        // drains vmcnt(0): staged data visible
#pragma unroll
    for (int s = 0; s < 2; ++s){            // k-slice of 32
#pragma unroll
      for (int t = 0; t < 2; ++t){          // k-step of 16 within slice
        bf16x8 af[2], bfr[2];
#pragma unroll
        for (int i = 0; i < 2; ++i) af[i]  = *(const bf16x8*)&As[s][apo[i] + t * 16];
#pragma unroll
        for (int i = 0; i < 2; ++i) bfr[i] = *(const bf16x8*)&Bs[s][bpo[i] + t * 16];
#pragma unroll
        for (int i = 0; i < 2; ++i)
#pragma unroll
          for (int j = 0; j < 2; ++j)
            acc[i][j] = __builtin_amdgcn_mfma_f32_32x32x16_bf16(af[i], bfr[j], acc[i][j], 0, 0, 0);
      }
    }
  }

  // epilogue. 32x32 C/D map: col=lane&31, row=(reg&3)+8*(reg>>2)+4*(lane>>5)
  int rbase = (lane >> 5) * 4;
#pragma unroll
  for (int i = 0; i < 2; ++i){
#pragma unroll
    for (int j = 0; j < 2; ++j){
      int n = n0 + wn * 64 + j * 32 + ln31;
#pragma unroll
      for (int r = 0; r < 16; ++r){
        int row = (r & 3) + 8 * (r >> 2) + rbase;
        int o = m0 + wm * 64 + i * 32 + row;
        size_t idx = ((size_t)(b * 512 + o)) * HWPIX + n;
        float v = acc[i][j][r] + noise[idx] + bias[o];
        out[idx] = (v >= 0.f) ? v : 0.2f * v;
      }
    }
  }
}

extern "C" void kernel_launch(void* const* d_in, const int* in_sizes, int n_in,
                              void* d_out, int out_size, void* d_ws, size_t ws_size,
                              hipStream_t stream) {
  const float* x        = (const float*)d_in[0];
  const float* w        = (const float*)d_in[1];
  const float* noise    = (const float*)d_in[2];
  const float* weight   = (const float*)d_in[3];
  const float* affine_w = (const float*)d_in[4];
  const float* affine_b = (const float*)d_in[5];
  const float* bias     = (const float*)d_in[6];
  float* out = (float*)d_out;

  // workspace: styles 16KB | wmod 37,748,736B | xpad 35,684,352B  (~73.5 MB)
  float* styles = (float*)d_ws;
  unsigned short* wmod = (unsigned short*)((char*)d_ws + 16384);
  unsigned short* xpad = (unsigned short*)((char*)d_ws + 16384 + 37748736ull);

  style_k<<<dim3(1024), 256, 0, stream>>>(w, affine_w, affine_b, styles);
  modw_k <<<dim3(512, 8), 256, 0, stream>>>(weight, styles, wmod);
  xpose_k<<<dim3(64, 8, 8), 256, 0, stream>>>(x, xpad);
  conv_gemm<<<dim3(1024), 256, 0, stream>>>(wmod, xpad, noise, bias, out);
}

// Round 5
// 336.913 us; speedup vs baseline: 1.1760x; 1.1760x over previous
//
#include <hip/hip_runtime.h>
#include <hip/hip_bf16.h>

// ModulatedConv2d: B=8, Cin=Cout=512, K=3, H=W=64, pad=1, groups=B.
// bf16 MFMA implicit GEMM per batch: C[512,4096] = Wmod[512,4608] x Im2col.
// k = tap*512 + cin; BK=64, 2-barrier K-loop (R2 structure), 16x16x32 MFMA.
// R5: block tile 256x128, wave tile 128x64 (8x4 frags) -> LDS-read FLOP/B
// 32 -> 42.7 (LDS BW was the tallest floor at 92us). Grid 512, b==XCD swizzle.

#define CIN   512
#define COUT  512
#define KDIM  4608        // 9 * 512
#define HWPIX 4096

typedef __attribute__((ext_vector_type(8))) __bf16 bf16x8;
typedef __attribute__((ext_vector_type(4))) float  f32x4;

__device__ __forceinline__ unsigned short f2bf(float f){
  union { float f; unsigned int u; } v; v.f = f;
  unsigned int u = v.u;
  u += 0x7fffu + ((u >> 16) & 1u);     // round-to-nearest-even
  return (unsigned short)(u >> 16);
}

#define GLDS16(g, l) __builtin_amdgcn_global_load_lds(                      \
    (const __attribute__((address_space(1))) unsigned int*)(g),             \
    (__attribute__((address_space(3))) unsigned int*)(l), 16, 0, 0)

// ---------------- styles: s[b][c] = dot(w[b], affine_w[c]) + ab[c] + 1 ----
__global__ void style_k(const float* __restrict__ w, const float* __restrict__ aw,
                        const float* __restrict__ ab, float* __restrict__ styles){
  int wid = threadIdx.x >> 6, lane = threadIdx.x & 63;
  int gid = blockIdx.x * 4 + wid;           // 0..4095 = b*512 + c
  int b = gid >> 9, c = gid & 511;
  const float* wb = w + b * 512;
  const float* ar = aw + c * 512;
  float sum = 0.f;
  for (int j = lane; j < 512; j += 64) sum += wb[j] * ar[j];
  for (int off = 32; off; off >>= 1) sum += __shfl_down(sum, off, 64);
  if (lane == 0) styles[gid] = sum + ab[c] + 1.0f;
}

// ------------- modulate + demodulate -> bf16 wmod[b][o][tap*512+cin] ------
__global__ void modw_k(const float* __restrict__ weight, const float* __restrict__ styles,
                       unsigned short* __restrict__ wmod){
  int o = blockIdx.x, b = blockIdx.y;
  int t = threadIdx.x;
  const float* wrow = weight + (size_t)o * KDIM;   // weight[0][o][i][ky][kx]
  const float* st   = styles + b * 512;
  __shared__ unsigned short sw[9 * 520];           // tap stride 520 (pad vs 512)
  __shared__ float red[4];
  float vals[18];
  float part = 0.f;
#pragma unroll
  for (int it = 0; it < 18; ++it){
    int idx = it * 256 + t;             // coalesced over threads
    int i = idx / 9;
    float v = wrow[idx] * st[i];
    vals[it] = v;
    part += v * v;
  }
  int wid = t >> 6, lane = t & 63;
  for (int off = 32; off; off >>= 1) part += __shfl_down(part, off, 64);
  if (lane == 0) red[wid] = part;
  __syncthreads();
  float d = rsqrtf(red[0] + red[1] + red[2] + red[3] + 1e-8f);
#pragma unroll
  for (int it = 0; it < 18; ++it){
    int idx = it * 256 + t;
    int i = idx / 9;
    int tap = idx - i * 9;
    sw[tap * 520 + i] = f2bf(vals[it] * d);
  }
  __syncthreads();
  unsigned int* orow32 = (unsigned int*)(wmod + ((size_t)(b * 512 + o)) * KDIM);
#pragma unroll
  for (int it = 0; it < 9; ++it){       // 2304 dwords, fully coalesced
    int u = it * 256 + t;
    int e = u * 2;
    int tap2 = e >> 9, i2 = e & 511;
    orow32[u] = *(const unsigned int*)&sw[tap2 * 520 + i2];
  }
}

// ----- transpose+pad: x[b][c][h][w] fp32 -> xpad[b][h+1][w+1][c] bf16 -----
// Also zeroes the pad border (replaces the memset dispatch).
__global__ void xpose_k(const float* __restrict__ x, unsigned short* __restrict__ xpad){
  int h = blockIdx.x, cg = blockIdx.y, b = blockIdx.z;
  int c0 = cg * 64;
  __shared__ unsigned short lds[64][66];   // [w][c]: writes 2-way (free), reads clean
  int t = threadIdx.x;
  const float* xb = x + (((size_t)(b * 512 + c0)) * 64 + h) * 64;
#pragma unroll
  for (int it = 0; it < 16; ++it){
    int idx = it * 256 + t;
    int cl = idx >> 6, wl = idx & 63;     // cl wave-uniform, wl = lane
    lds[wl][cl] = f2bf(xb[(size_t)cl * 4096 + wl]);
  }
  if (t < 64){
    int which = t >> 5;                   // 0: w=0, 1: w=65
    int ch2 = (t & 31) * 2;
    int wl = which ? 65 : 0;
    *(unsigned int*)&xpad[(((size_t)b * 66 + h + 1) * 66 + wl) * 512 + c0 + ch2] = 0u;
  }
  if (h == 0 || h == 63){                 // rows 0 / 65, all 66 w
    int row = (h == 0) ? 0 : 65;
    for (int u = t; u < 66 * 32; u += 256){
      int wl = u >> 5, ch2 = (u & 31) * 2;
      *(unsigned int*)&xpad[(((size_t)b * 66 + row) * 66 + wl) * 512 + c0 + ch2] = 0u;
    }
  }
  __syncthreads();
#pragma unroll
  for (int it = 0; it < 2; ++it){
    int idx = it * 256 + t;
    int wl = idx >> 3, ch = idx & 7;
    unsigned int u0 = *(const unsigned int*)&lds[wl][ch * 8 + 0];
    unsigned int u1 = *(const unsigned int*)&lds[wl][ch * 8 + 2];
    unsigned int u2 = *(const unsigned int*)&lds[wl][ch * 8 + 4];
    unsigned int u3 = *(const unsigned int*)&lds[wl][ch * 8 + 6];
    int off = ((b * 66 + h + 1) * 66 + (wl + 1)) * 512 + c0 + ch * 8;
    *(uint4*)&xpad[off] = make_uint4(u0, u1, u2, u3);
  }
}

// --------------------------- main conv GEMM ------------------------------
// grid 512 (b==XCD swizzle); 256x128 block tile, 4 waves of 128x64 (8x4 frags);
// BK=64, 2-barrier K-loop, 16x16x32 MFMA. LDS 48KB -> 2 blocks/CU.
__global__ __launch_bounds__(256, 2) void conv_gemm(
    const unsigned short* __restrict__ wmod, const unsigned short* __restrict__ xpad,
    const float* __restrict__ noise, const float* __restrict__ bias,
    float* __restrict__ out){
  __shared__ unsigned short As[2][256 * 32];   // [slice][m][k32]  16KB each
  __shared__ unsigned short Bs[2][128 * 32];   // [slice][n][k32]   8KB each
  // decode: per XCD one batch (b = xcd), both m-tiles, all 32 n-tiles.
  int g = blockIdx.x;
  int xcd = g & 7, sl = g >> 3;                // sl 0..63
  int b = xcd, mt = sl >> 5, nt = sl & 31;
  int m0 = mt * 256, n0 = nt * 128;
  int h0 = nt * 2;                             // 2 image rows per n-tile
  int tid = threadIdx.x, wid = tid >> 6, lane = tid & 63;
  int wm = wid >> 1, wn = wid & 1;             // wave tile: rows wm*128, cols wn*64
  int lr = lane >> 2;                          // row within 16-row staging group
  int lc = lane & 3;                           // 16B chunk within 64B row

  const unsigned short* wbase = wmod + ((size_t)(b * 512 + m0)) * KDIM;
  int aoffG[4];
#pragma unroll
  for (int i = 0; i < 4; ++i)
    aoffG[i] = ((wid * 64 + i * 16 + lr)) * KDIM + lc * 8;   // A rows wid*64..+63

  const unsigned short* xb = xpad + (size_t)b * 66 * 66 * 512;
  int boffG[2];
#pragma unroll
  for (int i = 0; i < 2; ++i){
    int p = wid * 32 + i * 16 + lr;                          // B rows wid*32..+31
    boffG[i] = ((h0 + (p >> 6) + 1) * 66 + ((p & 63) + 1)) * 512 + lc * 8;
  }
  int albase[4], blbase[2];
#pragma unroll
  for (int i = 0; i < 4; ++i) albase[i] = (wid * 64 + i * 16) * 32;  // wave-uniform
#pragma unroll
  for (int i = 0; i < 2; ++i) blbase[i] = (wid * 32 + i * 16) * 32;

  int fm = lane & 15;
  int k8 = (lane >> 4) * 8;
  int apo[8], bpo[4];
#pragma unroll
  for (int i = 0; i < 8; ++i) apo[i] = (wm * 128 + i * 16 + fm) * 32 + k8;
#pragma unroll
  for (int j = 0; j < 4; ++j) bpo[j] = (wn * 64 + j * 16 + fm) * 32 + k8;

  f32x4 acc[8][4];
#pragma unroll
  for (int i = 0; i < 8; ++i)
#pragma unroll
    for (int j = 0; j < 4; ++j) acc[i][j] = (f32x4){0.f, 0.f, 0.f, 0.f};

  for (int ks = 0; ks < 72; ++ks){
    int tap = ks >> 3;                      // 64 | 512: one tap per BK=64 step
    int c0  = (ks & 7) << 6;
    int k0  = (tap << 9) + c0;              // == ks*64
    int dy3 = tap / 3;
    int bshift = (((dy3 - 1) * 66 + (tap - dy3 * 3 - 1)) << 9) + c0;
    __syncthreads();                        // prior iter's ds_reads retired
#pragma unroll
    for (int i = 0; i < 4; ++i){
      GLDS16(wbase + aoffG[i] + k0,      &As[0][albase[i]]);
      GLDS16(wbase + aoffG[i] + k0 + 32, &As[1][albase[i]]);
    }
#pragma unroll
    for (int i = 0; i < 2; ++i){
      GLDS16(xb + boffG[i] + bshift,      &Bs[0][blbase[i]]);
      GLDS16(xb + boffG[i] + bshift + 32, &Bs[1][blbase[i]]);
    }
    __syncthreads();                        // drains vmcnt(0): staged data visible
#pragma unroll
    for (int s = 0; s < 2; ++s){
      bf16x8 af[8], bfr[4];
#pragma unroll
      for (int i = 0; i < 8; ++i) af[i]  = *(const bf16x8*)&As[s][apo[i]];
#pragma unroll
      for (int j = 0; j < 4; ++j) bfr[j] = *(const bf16x8*)&Bs[s][bpo[j]];
#pragma unroll
      for (int i = 0; i < 8; ++i)
#pragma unroll
        for (int j = 0; j < 4; ++j)
          acc[i][j] = __builtin_amdgcn_mfma_f32_16x16x32_bf16(af[i], bfr[j], acc[i][j], 0, 0, 0);
    }
  }

  // epilogue: + noise + bias, leaky relu 0.2. C/D map: row=(lane>>4)*4+reg, col=lane&15
  int quad = lane >> 4;
#pragma unroll
  for (int i = 0; i < 8; ++i){
    int o_base = m0 + wm * 128 + i * 16 + quad * 4;
#pragma unroll
    for (int j = 0; j < 4; ++j){
      int n = n0 + wn * 64 + j * 16 + fm;
#pragma unroll
      for (int r = 0; r < 4; ++r){
        int o = o_base + r;
        size_t idx = ((size_t)(b * 512 + o)) * HWPIX + n;
        float v = acc[i][j][r] + noise[idx] + bias[o];
        out[idx] = (v >= 0.f) ? v : 0.2f * v;
      }
    }
  }
}

extern "C" void kernel_launch(void* const* d_in, const int* in_sizes, int n_in,
                              void* d_out, int out_size, void* d_ws, size_t ws_size,
                              hipStream_t stream) {
  const float* x        = (const float*)d_in[0];
  const float* w        = (const float*)d_in[1];
  const float* noise    = (const float*)d_in[2];
  const float* weight   = (const float*)d_in[3];
  const float* affine_w = (const float*)d_in[4];
  const float* affine_b = (const float*)d_in[5];
  const float* bias     = (const float*)d_in[6];
  float* out = (float*)d_out;

  // workspace: styles 16KB | wmod 37,748,736B | xpad 35,684,352B  (~73.5 MB)
  float* styles = (float*)d_ws;
  unsigned short* wmod = (unsigned short*)((char*)d_ws + 16384);
  unsigned short* xpad = (unsigned short*)((char*)d_ws + 16384 + 37748736ull);

  style_k<<<dim3(1024), 256, 0, stream>>>(w, affine_w, affine_b, styles);
  modw_k <<<dim3(512, 8), 256, 0, stream>>>(weight, styles, wmod);
  xpose_k<<<dim3(64, 8, 8), 256, 0, stream>>>(x, xpad);
  conv_gemm<<<dim3(512), 256, 0, stream>>>(wmod, xpad, noise, bias, out);
}